// Round 9
// baseline (1272.695 us; speedup 1.0000x reference)
//
#include <hip/hip_runtime.h>
#include <cstdint>

#define N_NODES 50000
#define N_EDGES 800000
#define N_GRAPHS 1024
#define NODE_IN 128
#define HID 300
#define DEPTH 5
#define READOUT 1024
#define PSTR 320   // plane row stride (elements): 640B rows
#define XSTR 384   // stacked proj plane stride

typedef float f32x4 __attribute__((ext_vector_type(4)));
typedef short bf16x8 __attribute__((ext_vector_type(8)));
typedef unsigned short us8 __attribute__((ext_vector_type(8)));

__device__ inline unsigned short f2bf(float v) {
    unsigned u = __float_as_uint(v);
    unsigned r = u + 0x7FFFu + ((u >> 16) & 1u);
    return (unsigned short)(r >> 16);
}
__device__ inline float bf2f(unsigned short h) {
    return __uint_as_float((unsigned)h << 16);
}
__device__ inline float bflo(unsigned u) { return __uint_as_float(u << 16); }
__device__ inline float bfhi(unsigned u) { return __uint_as_float(u & 0xFFFF0000u); }
__device__ inline unsigned packbf(float a, float b) {
    return (unsigned)f2bf(a) | ((unsigned)f2bf(b) << 16);
}

// ---------------------------------------------------------------- CSR build (merged)
__global__ void hist2(const int* __restrict__ dst, int* __restrict__ cnt,
                      const int* __restrict__ batch, int* __restrict__ gcnt) {
    int i = blockIdx.x * blockDim.x + threadIdx.x;
    if (i < N_EDGES) atomicAdd(&cnt[dst[i]], 1);
    else if (i < N_EDGES + N_NODES) atomicAdd(&gcnt[batch[i - N_EDGES]], 1);
}

__global__ __launch_bounds__(256)
void scan_block2(const int* __restrict__ cnt, int* __restrict__ offs, int* __restrict__ bsum,
                 const int* __restrict__ gcnt, int* __restrict__ goffs, int* __restrict__ gsum,
                 int nbn) {
    __shared__ int buf[256];
    int b = blockIdx.x;
    const int* in; int* out; int* bs; int n; int bi;
    if (b < nbn) { in = cnt; out = offs; bs = bsum; n = N_NODES; bi = b; }
    else { in = gcnt; out = goffs; bs = gsum; n = N_GRAPHS; bi = b - nbn; }
    int i = bi * 256 + (int)threadIdx.x;
    int v = (i < n) ? in[i] : 0;
    buf[threadIdx.x] = v;
    __syncthreads();
    for (int off = 1; off < 256; off <<= 1) {
        int t = ((int)threadIdx.x >= off) ? buf[threadIdx.x - off] : 0;
        __syncthreads();
        buf[threadIdx.x] += t;
        __syncthreads();
    }
    if (i < n) out[i] = buf[threadIdx.x] - v;
    if (threadIdx.x == 255) bs[bi] = buf[255];
}

__global__ __launch_bounds__(256)
void scan_base2(const int* __restrict__ bsum, int* __restrict__ bbase, int nbn, int* __restrict__ tot_n,
                const int* __restrict__ gsum, int* __restrict__ gbase, int nbg, int* __restrict__ tot_g) {
    __shared__ int buf[256];
    const int* bs; int* bb; int nb; int* tot;
    if (blockIdx.x == 0) { bs = bsum; bb = bbase; nb = nbn; tot = tot_n; }
    else { bs = gsum; bb = gbase; nb = nbg; tot = tot_g; }
    int v = ((int)threadIdx.x < nb) ? bs[threadIdx.x] : 0;
    buf[threadIdx.x] = v;
    __syncthreads();
    for (int off = 1; off < 256; off <<= 1) {
        int t = ((int)threadIdx.x >= off) ? buf[threadIdx.x - off] : 0;
        __syncthreads();
        buf[threadIdx.x] += t;
        __syncthreads();
    }
    if ((int)threadIdx.x < nb) bb[threadIdx.x] = buf[threadIdx.x] - v;
    if (threadIdx.x == 255) *tot = buf[255];
}

__global__ void scan_add2(int* __restrict__ offs, const int* __restrict__ bbase,
                          int* __restrict__ cursor,
                          int* __restrict__ goffs, const int* __restrict__ gbase, int nbn) {
    int b = blockIdx.x;
    if (b < nbn) {
        int i = b * 256 + (int)threadIdx.x;
        if (i < N_NODES) {
            int o = offs[i] + bbase[b];
            offs[i] = o;
            cursor[i] = o;
        }
    } else {
        int bi = b - nbn;
        int i = bi * 256 + (int)threadIdx.x;
        if (i < N_GRAPHS) goffs[i] += gbase[bi];
    }
}

__global__ void scatter_kernel(const int* __restrict__ src, const int* __restrict__ dst,
                               int* __restrict__ cursor, int* __restrict__ csr, int n) {
    int i = blockIdx.x * blockDim.x + threadIdx.x;
    if (i < n) {
        int p = atomicAdd(&cursor[dst[i]], 1);
        csr[p] = src[i];
    }
}

// ---------------------------------------------------------------- weight pre-split (all in one)
// z<10: hidden W1/W2 -> hi/lo [320][320]; z==10: W_sp -> [1280][320]; z==11: Wproj -> Bp [320][384]
__global__ __launch_bounds__(256)
void split_all(const float* __restrict__ W1, const float* __restrict__ W2,
               const float* __restrict__ Wsp, const float* __restrict__ Wproj,
               unsigned short* __restrict__ w1H, unsigned short* __restrict__ w1L,
               unsigned short* __restrict__ w2H, unsigned short* __restrict__ w2L,
               unsigned short* __restrict__ spH, unsigned short* __restrict__ spL,
               unsigned short* __restrict__ Bp) {
    __shared__ float tile[32][33];
    const int LAYER_SZ = 320 * 320;
    int z = blockIdx.z;
    const float* W; unsigned short* H = nullptr; unsigned short* L = nullptr;
    int K, N, KP;
    if (z < 10) {
        if (blockIdx.x >= 10) return;
        int l = z % 5;
        W = (z < 5 ? W1 : W2) + (size_t)l * HID * HID;
        H = (z < 5 ? w1H : w2H) + (size_t)l * LAYER_SZ;
        L = (z < 5 ? w1L : w2L) + (size_t)l * LAYER_SZ;
        K = HID; N = HID; KP = 320;
    } else if (z == 10) {
        W = Wsp; H = spH; L = spL; K = HID; N = READOUT; KP = 320;
    } else {
        if (blockIdx.x >= 10 || blockIdx.y >= 4) return;
        W = Wproj; K = NODE_IN; N = HID; KP = XSTR;
    }
    int n0 = blockIdx.x * 32, k0 = blockIdx.y * 32;
    int tx = threadIdx.x & 31, ty = threadIdx.x >> 5;
#pragma unroll
    for (int r = 0; r < 4; ++r) {
        int k = k0 + ty + r * 8, n = n0 + tx;
        tile[ty + r * 8][tx] = (k < K && n < N) ? W[(size_t)k * N + n] : 0.f;
    }
    __syncthreads();
#pragma unroll
    for (int r = 0; r < 4; ++r) {
        int n = n0 + ty + r * 8, k = k0 + tx;
        float v = tile[tx][ty + r * 8];
        unsigned short hb = f2bf(v);
        unsigned short lb = f2bf(v - bf2f(hb));
        if (z < 11) {
            H[(size_t)n * KP + k] = hb;
            L[(size_t)n * KP + k] = lb;
        } else {
            Bp[(size_t)n * XSTR + k] = hb;
            Bp[(size_t)n * XSTR + 128 + k] = hb;
            Bp[(size_t)n * XSTR + 256 + k] = lb;
        }
    }
}

// x -> xs plane [50000][384] = [xh | xl | xh]
__global__ void split_x(const float* __restrict__ x, unsigned short* __restrict__ xs) {
    int i = blockIdx.x * blockDim.x + threadIdx.x;
    if (i >= N_NODES * 64) return;
    int row = i >> 6, c = i & 63;
    float2 v = *(const float2*)&x[(size_t)row * NODE_IN + 2 * c];
    unsigned short h0 = f2bf(v.x), h1 = f2bf(v.y);
    unsigned short l0 = f2bf(v.x - bf2f(h0)), l1 = f2bf(v.y - bf2f(h1));
    unsigned hp = (unsigned)h0 | ((unsigned)h1 << 16);
    unsigned lp = (unsigned)l0 | ((unsigned)l1 << 16);
    unsigned* o = (unsigned*)(xs + (size_t)row * XSTR);
    o[c] = hp;
    o[64 + c] = lp;
    o[128 + c] = hp;
}

#define BSWZ(r, c) ((c) ^ (((r) >> 1) & 3))

// ---------------------------------------------------------------- fused GIN layer
// nxt = act2( relu( (cur + A*cur) @ (W1H+W1L) + b1 ) @ (W2H+W2L) + b2 )
// 391 blocks x 128 rows, 512 thr (8 waves, 2M x 4N). Gather phase fills At directly.
__global__ __launch_bounds__(512)
void gin_layer(const unsigned short* __restrict__ h, const int* __restrict__ offs,
               const int* __restrict__ csr, int M,
               const unsigned short* __restrict__ B1H, const unsigned short* __restrict__ B1L,
               const float* __restrict__ b1,
               const unsigned short* __restrict__ B2H, const unsigned short* __restrict__ B2L,
               const float* __restrict__ b2,
               unsigned short* __restrict__ Op, int act2) {
    __shared__ __align__(16) unsigned short At[128 * 320];   // 80 KB
    __shared__ __align__(16) unsigned short Bs[2 * 10240];   // 40 KB

    const int tid = threadIdx.x;
    const int bm = blockIdx.x * 128;
    const int wid = tid >> 6, lane = tid & 63;
    const int wm = wid >> 2, wn = wid & 3;
    const int lr = lane & 15, lk = lane >> 4;

    float b1v[5], b2v[5];
#pragma unroll
    for (int n = 0; n < 5; ++n) {
        int col = wn * 80 + n * 16 + lr;
        b1v[n] = (col < HID) ? b1[col] : 0.f;
        b2v[n] = (col < HID) ? b2[col] : 0.f;
    }

    size_t bofs[5]; int bldso[5]; bool bpl[5];
#pragma unroll
    for (int i = 0; i < 5; ++i) {
        int qq = i * 512 + tid;
        bool pl = qq >= 1280;
        int q2 = qq - (pl ? 1280 : 0);
        int r = q2 >> 2, c = q2 & 3;
        bpl[i] = pl;
        bofs[i] = (size_t)r * 320 + c * 8;
        bldso[i] = (pl ? 10240 : 0) + r * 32 + BSWZ(r, c) * 8;
    }

    us8 vB[5];
    auto LOADB = [&](const unsigned short* BH, const unsigned short* BL, int t) {
        int k0 = t * 32;
#pragma unroll
        for (int i = 0; i < 5; ++i) {
            const unsigned short* base = bpl[i] ? BL : BH;
            vB[i] = *(const us8*)&base[bofs[i] + k0];
        }
    };

    // issue GEMM1's first B tile now; completes during gather
    LOADB(B1H, B1L, 0);

    // ---- gather phase: agg rows straight into swizzled At (16 nodes/wave) ----
    unsigned* At_dw = (unsigned*)At;
    for (int j = 0; j < 16; ++j) {
        int row = wid * 16 + j;
        int g = bm + row;
        float a0 = 0.f, a1 = 0.f, a2 = 0.f, a3 = 0.f, a4 = 0.f, a5 = 0.f;
        if (g < M) {
            const unsigned* rr = (const unsigned*)(h + (size_t)g * PSTR);
            uint2 u = *(const uint2*)&rr[2 * lane];
            unsigned t = (lane < 32) ? rr[128 + lane] : 0u;
            a0 = bflo(u.x); a1 = bfhi(u.x);
            a2 = bflo(u.y); a3 = bfhi(u.y);
            a4 = bflo(t);   a5 = bfhi(t);
            int s = offs[g], e = offs[g + 1];
            int k = s;
            for (; k + 3 < e; k += 4) {
                const unsigned* r0 = (const unsigned*)(h + (size_t)csr[k] * PSTR);
                const unsigned* r1 = (const unsigned*)(h + (size_t)csr[k + 1] * PSTR);
                const unsigned* r2 = (const unsigned*)(h + (size_t)csr[k + 2] * PSTR);
                const unsigned* r3 = (const unsigned*)(h + (size_t)csr[k + 3] * PSTR);
                uint2 x0 = *(const uint2*)&r0[2 * lane];
                uint2 x1 = *(const uint2*)&r1[2 * lane];
                uint2 x2 = *(const uint2*)&r2[2 * lane];
                uint2 x3 = *(const uint2*)&r3[2 * lane];
                unsigned t0 = 0, t1 = 0, t2 = 0, t3 = 0;
                if (lane < 32) {
                    t0 = r0[128 + lane]; t1 = r1[128 + lane];
                    t2 = r2[128 + lane]; t3 = r3[128 + lane];
                }
                a0 += bflo(x0.x) + bflo(x1.x) + bflo(x2.x) + bflo(x3.x);
                a1 += bfhi(x0.x) + bfhi(x1.x) + bfhi(x2.x) + bfhi(x3.x);
                a2 += bflo(x0.y) + bflo(x1.y) + bflo(x2.y) + bflo(x3.y);
                a3 += bfhi(x0.y) + bfhi(x1.y) + bfhi(x2.y) + bfhi(x3.y);
                a4 += bflo(t0) + bflo(t1) + bflo(t2) + bflo(t3);
                a5 += bfhi(t0) + bfhi(t1) + bfhi(t2) + bfhi(t3);
            }
            for (; k < e; ++k) {
                const unsigned* r4 = (const unsigned*)(h + (size_t)csr[k] * PSTR);
                uint2 u4 = *(const uint2*)&r4[2 * lane];
                unsigned t4 = (lane < 32) ? r4[128 + lane] : 0u;
                a0 += bflo(u4.x); a1 += bfhi(u4.x);
                a2 += bflo(u4.y); a3 += bfhi(u4.y);
                a4 += bflo(t4);   a5 += bfhi(t4);
            }
        }
        // swizzled LDS write: cols 4*lane..+3 and tail 256+2*lane
        int rb = row * 160;
        int c0 = ((lane >> 1) ^ (row & 7)) * 4 + (lane & 1) * 2;
        uint2 wv; wv.x = packbf(a0, a1); wv.y = packbf(a2, a3);
        *(uint2*)&At_dw[rb + c0] = wv;
        if (lane < 32) {
            int cc = (32 + (lane >> 2)) ^ (row & 7);
            At_dw[rb + cc * 4 + (lane & 3)] = (lane < 22) ? packbf(a4, a5) : 0u;
        }
    }

    f32x4 acc[4][5];

    auto RUN = [&](const unsigned short* BH, const unsigned short* BL) {
        for (int t = 0; t < 10; ++t) {
            __syncthreads();                     // Bs free / At writes visible
#pragma unroll
            for (int i = 0; i < 5; ++i) *(us8*)&Bs[bldso[i]] = vB[i];
            if (t < 9) LOADB(BH, BL, t + 1);     // in flight under compute
            __syncthreads();                     // Bs ready
            bf16x8 aS[4];
#pragma unroll
            for (int m = 0; m < 4; ++m) {
                int row = wm * 64 + m * 16 + lr;
                int c = t * 4 + lk;
                aS[m] = *(const bf16x8*)&At[row * 320 + (c ^ (row & 7)) * 8];
            }
#pragma unroll
            for (int n = 0; n < 5; ++n) {
                int rb2 = wn * 80 + n * 16 + lr;
                int sc = rb2 * 32 + BSWZ(rb2, lk) * 8;
                bf16x8 bh = *(const bf16x8*)&Bs[sc];
                bf16x8 bl = *(const bf16x8*)&Bs[10240 + sc];
#pragma unroll
                for (int m = 0; m < 4; ++m) {
                    acc[m][n] = __builtin_amdgcn_mfma_f32_16x16x32_bf16(aS[m], bh, acc[m][n], 0, 0, 0);
                    acc[m][n] = __builtin_amdgcn_mfma_f32_16x16x32_bf16(aS[m], bl, acc[m][n], 0, 0, 0);
                }
            }
        }
    };

    // ---- GEMM1 ----
#pragma unroll
    for (int m = 0; m < 4; ++m)
#pragma unroll
        for (int n = 0; n < 5; ++n) acc[m][n] = (f32x4)0.f;
    RUN(B1H, B1L);

    LOADB(B2H, B2L, 0);          // prefetch GEMM2's first tile

    // ---- T = relu(acc + b1) -> At ----
    __syncthreads();
#pragma unroll
    for (int n = 0; n < 5; ++n) {
        int col = wn * 80 + n * 16 + lr;
        int cc = col >> 3, cp = col & 7;
        float bv = b1v[n];
        bool vc = col < HID;
#pragma unroll
        for (int m = 0; m < 4; ++m) {
#pragma unroll
            for (int p = 0; p < 4; ++p) {
                int row = wm * 64 + m * 16 + lk * 4 + p;
                float v = vc ? fmaxf(acc[m][n][p] + bv, 0.f) : 0.f;
                At[row * 320 + ((cc ^ (row & 7)) * 8) + cp] = f2bf(v);
            }
        }
    }

    // ---- GEMM2 ----
#pragma unroll
    for (int m = 0; m < 4; ++m)
#pragma unroll
        for (int n = 0; n < 5; ++n) acc[m][n] = (f32x4)0.f;
    RUN(B2H, B2L);

    // ---- epilogue: act2(acc + b2) -> At -> coalesced stores ----
    __syncthreads();
#pragma unroll
    for (int n = 0; n < 5; ++n) {
        int col = wn * 80 + n * 16 + lr;
        int cc = col >> 3, cp = col & 7;
        float bv = b2v[n];
        bool vc = col < HID;
#pragma unroll
        for (int m = 0; m < 4; ++m) {
#pragma unroll
            for (int p = 0; p < 4; ++p) {
                int row = wm * 64 + m * 16 + lk * 4 + p;
                float v = vc ? (acc[m][n][p] + bv) : 0.f;
                if (act2) v = fmaxf(v, 0.f);
                At[row * 320 + ((cc ^ (row & 7)) * 8) + cp] = f2bf(v);
            }
        }
    }
    __syncthreads();
#pragma unroll
    for (int i = 0; i < 10; ++i) {
        int g = i * 512 + tid;
        int row = g / 40, c = g - row * 40;
        int grow = bm + row;
        if (grow < M)
            *(us8*)&Op[(size_t)grow * PSTR + c * 8] =
                *(const us8*)&At[row * 320 + (c ^ (row & 7)) * 8];
    }
}

// ---------------------------------------------------------------- projection GEMM (dbuf, plane out)
template<int NPL>
__global__ __launch_bounds__(512)
void gemm_plane4(const unsigned short* __restrict__ Ap, int astr, int M, int KP,
                 const unsigned short* __restrict__ BH, const unsigned short* __restrict__ BL,
                 const float* __restrict__ bias, unsigned short* __restrict__ Op, int act) {
    constexpr int BITER = (NPL * 1280 + 511) / 512;
    __shared__ __align__(16) unsigned short As[2][256 * 40];
    __shared__ __align__(16) unsigned short Bs[2][NPL * 10240];

    const int tid = threadIdx.x;
    const int bm = blockIdx.x * 256;
    const int wid = tid >> 6, lane = tid & 63;
    const int wm = wid >> 2, wn = wid & 3;
    const int lr = lane & 15, lk = lane >> 4;
    const int arow = tid >> 1, ach = (tid & 1) * 2;
    int agr = bm + arow; if (agr >= M) agr = M - 1;
    const unsigned short* aSrc = Ap + (size_t)agr * astr + ach * 8;

    const unsigned short* bsrc[BITER];
    int bldso[BITER];
    bool bval[BITER];
#pragma unroll
    for (int i = 0; i < BITER; ++i) {
        int qq = i * 512 + tid;
        bval[i] = qq < NPL * 1280;
        int p = (NPL == 2 && qq >= 1280) ? 1 : 0;
        int q2 = qq - p * 1280;
        int r = q2 >> 2, c = q2 & 3;
        const unsigned short* base = p ? BL : BH;
        bsrc[i] = base + (size_t)r * KP + c * 8;
        bldso[i] = p * 10240 + r * 32 + BSWZ(r, c) * 8;
    }

    f32x4 acc[8][5];
#pragma unroll
    for (int m = 0; m < 8; ++m)
#pragma unroll
        for (int n = 0; n < 5; ++n) acc[m][n] = (f32x4)0.f;

    us8 vA0, vA1, vB[BITER];
    auto LOADS = [&](int t) {
        int k0 = t * 32;
        vA0 = *(const us8*)&aSrc[k0];
        vA1 = *(const us8*)&aSrc[k0 + 8];
#pragma unroll
        for (int i = 0; i < BITER; ++i)
            if (bval[i]) vB[i] = *(const us8*)&bsrc[i][k0];
    };
    auto WRITE = [&](int b) {
        *(us8*)&As[b][arow * 40 + ach * 8] = vA0;
        *(us8*)&As[b][arow * 40 + ach * 8 + 8] = vA1;
#pragma unroll
        for (int i = 0; i < BITER; ++i)
            if (bval[i]) *(us8*)&Bs[b][bldso[i]] = vB[i];
    };

    const int nt = KP / 32;
    LOADS(0);
    WRITE(0);
    int buf = 0;
    for (int t = 0; t < nt; ++t) {
        bool more = (t + 1 < nt);
        if (more) LOADS(t + 1);
        __syncthreads();
        bf16x8 aS[8];
#pragma unroll
        for (int m = 0; m < 8; ++m)
            aS[m] = *(const bf16x8*)&As[buf][(wm * 128 + m * 16 + lr) * 40 + lk * 8];
#pragma unroll
        for (int n = 0; n < 5; ++n) {
            int rb = wn * 80 + n * 16 + lr;
            int sc = rb * 32 + BSWZ(rb, lk) * 8;
            bf16x8 bh = *(const bf16x8*)&Bs[buf][sc];
#pragma unroll
            for (int m = 0; m < 8; ++m)
                acc[m][n] = __builtin_amdgcn_mfma_f32_16x16x32_bf16(aS[m], bh, acc[m][n], 0, 0, 0);
            if (NPL == 2) {
                bf16x8 bl = *(const bf16x8*)&Bs[buf][10240 + sc];
#pragma unroll
                for (int m = 0; m < 8; ++m)
                    acc[m][n] = __builtin_amdgcn_mfma_f32_16x16x32_bf16(aS[m], bl, acc[m][n], 0, 0, 0);
            }
        }
        if (more) WRITE(buf ^ 1);
        buf ^= 1;
    }
#pragma unroll
    for (int n = 0; n < 5; ++n) {
        int col = wn * 80 + n * 16 + lr;
        bool vc = col < HID;
        float bv = vc ? bias[col] : 0.f;
#pragma unroll
        for (int m = 0; m < 8; ++m) {
            int rbase = bm + wm * 128 + m * 16 + lk * 4;
#pragma unroll
            for (int p = 0; p < 4; ++p) {
                int row = rbase + p;
                if (row >= M) continue;
                float v = vc ? (acc[m][n][p] + bv) : 0.f;
                if (act == 1) v = fmaxf(v, 0.f);
                Op[(size_t)row * PSTR + col] = f2bf(v);
            }
        }
    }
}

// ---------------------------------------------------------------- GEMM: fp32 A (readout only)
__global__ __launch_bounds__(256)
void gemm_f32A(const float* __restrict__ A, int lda, int M, int K, int KP,
               const unsigned short* __restrict__ BH, const unsigned short* __restrict__ BL, int KPB,
               const float* __restrict__ bias, int N,
               float* __restrict__ C, int ldc, int act, const float* __restrict__ prelu) {
    __shared__ __align__(16) unsigned short AsH[64 * 40];
    __shared__ __align__(16) unsigned short AsL[64 * 40];
    __shared__ __align__(16) unsigned short BsH[320 * 40];
    __shared__ __align__(16) unsigned short BsL[320 * 40];

    const int tid = threadIdx.x;
    const int bm = blockIdx.y * 64;
    const int bn = blockIdx.x * 320;
    const int wid = tid >> 6, lane = tid & 63;
    const int lr = lane & 15, lk = lane >> 4;
    const int ar = tid >> 2, ac = tid & 3;

    f32x4 acc[4][5];
#pragma unroll
    for (int m = 0; m < 4; ++m)
#pragma unroll
        for (int n = 0; n < 5; ++n) acc[m][n] = (f32x4)0.f;

    for (int k0 = 0; k0 < KP; k0 += 32) {
        {
            int gm = bm + ar;
            int k = k0 + ac * 8;
            float v[8];
#pragma unroll
            for (int j = 0; j < 8; ++j) v[j] = 0.f;
            if (gm < M) {
                if (k + 7 < K) {
                    float4 p0 = *(const float4*)&A[(size_t)gm * lda + k];
                    float4 p1 = *(const float4*)&A[(size_t)gm * lda + k + 4];
                    v[0] = p0.x; v[1] = p0.y; v[2] = p0.z; v[3] = p0.w;
                    v[4] = p1.x; v[5] = p1.y; v[6] = p1.z; v[7] = p1.w;
                } else {
#pragma unroll
                    for (int j = 0; j < 8; ++j)
                        if (k + j < K) v[j] = A[(size_t)gm * lda + k + j];
                }
            }
            us8 h, l;
#pragma unroll
            for (int j = 0; j < 8; ++j) {
                unsigned short hb = f2bf(v[j]);
                h[j] = hb;
                l[j] = f2bf(v[j] - bf2f(hb));
            }
            *(us8*)&AsH[ar * 40 + ac * 8] = h;
            *(us8*)&AsL[ar * 40 + ac * 8] = l;
        }
#pragma unroll
        for (int p = 0; p < 5; ++p) {
            int r = ar + p * 64;
            size_t gb = (size_t)(bn + r) * KPB + k0 + ac * 8;
            *(us8*)&BsH[r * 40 + ac * 8] = *(const us8*)&BH[gb];
            *(us8*)&BsL[r * 40 + ac * 8] = *(const us8*)&BL[gb];
        }
        __syncthreads();
        bf16x8 aH[4], aL[4];
#pragma unroll
        for (int m = 0; m < 4; ++m) {
            aH[m] = *(const bf16x8*)&AsH[(m * 16 + lr) * 40 + lk * 8];
            aL[m] = *(const bf16x8*)&AsL[(m * 16 + lr) * 40 + lk * 8];
        }
#pragma unroll
        for (int n = 0; n < 5; ++n) {
            int r = wid * 80 + n * 16 + lr;
            bf16x8 bh = *(const bf16x8*)&BsH[r * 40 + lk * 8];
            bf16x8 bl = *(const bf16x8*)&BsL[r * 40 + lk * 8];
#pragma unroll
            for (int m = 0; m < 4; ++m) {
                acc[m][n] = __builtin_amdgcn_mfma_f32_16x16x32_bf16(aH[m], bh, acc[m][n], 0, 0, 0);
                acc[m][n] = __builtin_amdgcn_mfma_f32_16x16x32_bf16(aH[m], bl, acc[m][n], 0, 0, 0);
                acc[m][n] = __builtin_amdgcn_mfma_f32_16x16x32_bf16(aL[m], bh, acc[m][n], 0, 0, 0);
            }
        }
        __syncthreads();
    }
    float slope = (act == 2) ? prelu[0] : 0.f;
#pragma unroll
    for (int n = 0; n < 5; ++n) {
        int col = bn + wid * 80 + n * 16 + lr;
        bool vc = col < N;
        float bv = vc ? bias[col] : 0.f;
#pragma unroll
        for (int m = 0; m < 4; ++m) {
            int rbase = bm + m * 16 + lk * 4;
#pragma unroll
            for (int p = 0; p < 4; ++p) {
                int row = rbase + p;
                if (row >= M) continue;
                float v = vc ? (acc[m][n][p] + bv) : 0.f;
                if (act == 1) v = fmaxf(v, 0.f);
                else if (act == 2) v = (v >= 0.f) ? v : slope * v;
                if (vc) C[(size_t)row * ldc + col] = v;
            }
        }
    }
}

// ---------------------------------------------------------------- segmented pool
__global__ __launch_bounds__(64)
void pool_seg(const unsigned short* __restrict__ h, const int* __restrict__ goffs,
              float* __restrict__ pooled) {
    int g = blockIdx.x;
    int lane = threadIdx.x;
    int s = goffs[g], e = goffs[g + 1];
    float a0 = 0.f, a1 = 0.f, a2 = 0.f, a3 = 0.f, a4 = 0.f, a5 = 0.f;
    for (int node = s; node < e; ++node) {
        const unsigned* r = (const unsigned*)(h + (size_t)node * PSTR);
        uint2 u = *(const uint2*)&r[2 * lane];
        unsigned t = (lane < 32) ? r[128 + lane] : 0u;
        a0 += bflo(u.x); a1 += bfhi(u.x);
        a2 += bflo(u.y); a3 += bfhi(u.y);
        a4 += bflo(t);   a5 += bfhi(t);
    }
    float* pr = pooled + (size_t)g * PSTR;
    *(float4*)&pr[4 * lane] = make_float4(a0, a1, a2, a3);
    if (lane < 32) *(float2*)&pr[256 + 2 * lane] = make_float2(a4, a5);
}

// ---------------------------------------------------------------- launch
extern "C" void kernel_launch(void* const* d_in, const int* in_sizes, int n_in,
                              void* d_out, int out_size, void* d_ws, size_t ws_size,
                              hipStream_t stream) {
    const float* x      = (const float*)d_in[0];
    const int*   eidx   = (const int*)d_in[1];
    const int*   batch  = (const int*)d_in[2];
    const float* W_proj = (const float*)d_in[3];
    const float* b_proj = (const float*)d_in[4];
    const float* W1     = (const float*)d_in[5];
    const float* b1     = (const float*)d_in[6];
    const float* W2     = (const float*)d_in[7];
    const float* b2     = (const float*)d_in[8];
    const float* W_sp   = (const float*)d_in[9];
    const float* b_sp   = (const float*)d_in[10];
    const float* prelu  = (const float*)d_in[11];

    const int* src = eidx;
    const int* dst = eidx + N_EDGES;

    const size_t PLANE  = (size_t)N_NODES * PSTR + 64;
    const size_t XPLANE = (size_t)N_NODES * XSTR + 64;
    const int LAYER_SZ = 320 * 320;
    const int SP_SZ    = 1280 * 320;
    const int BP_SZ    = 320 * XSTR;
    const int NB  = (N_NODES + 255) / 256;   // 196
    const int NBG = (N_GRAPHS + 255) / 256;  // 4

    unsigned short* hA  = (unsigned short*)d_ws;       // PLANE
    unsigned short* hBx = hA + PLANE;                  // XPLANE (xs overlay)
    unsigned short* xs  = hBx;
    float* pooled = (float*)(hBx + XPLANE);
    unsigned short* w1H = (unsigned short*)(pooled + (size_t)N_GRAPHS * PSTR + 16);
    unsigned short* w1L = w1H + 5 * (size_t)LAYER_SZ;
    unsigned short* w2H = w1L + 5 * (size_t)LAYER_SZ;
    unsigned short* w2L = w2H + 5 * (size_t)LAYER_SZ;
    unsigned short* spH = w2L + 5 * (size_t)LAYER_SZ;
    unsigned short* spL = spH + SP_SZ;
    unsigned short* Bp  = spL + SP_SZ;
    int* cnt    = (int*)(((uintptr_t)(Bp + BP_SZ) + 15) & ~(uintptr_t)15);
    int* gcnt   = cnt + N_NODES;               // contiguous with cnt (single memset)
    int* bsum   = gcnt + N_GRAPHS;
    int* bbase  = bsum + 256;
    int* gsum   = bbase + 256;
    int* gbase  = gsum + 256;
    int* offs   = gbase + 256;
    int* goffs  = offs + N_NODES + 1;
    int* cursor = goffs + N_GRAPHS + 1;
    int* csr    = cursor + N_NODES;
    size_t needed = (size_t)((uintptr_t)(csr + N_EDGES) - (uintptr_t)d_ws);
    if (ws_size < needed) return;

    // ---- weight pre-split (one launch) ----
    split_all<<<dim3(40, 10, 12), 256, 0, stream>>>(W1, W2, W_sp, W_proj,
                                                    w1H, w1L, w2H, w2L, spH, spL, Bp);
    // ---- input split ----
    split_x<<<(N_NODES * 64 + 255) / 256, 256, 0, stream>>>(x, xs);

    // ---- CSR + graph offsets (merged chains) ----
    hipMemsetAsync(cnt, 0, (N_NODES + N_GRAPHS) * sizeof(int), stream);
    hist2<<<(N_EDGES + N_NODES + 255) / 256, 256, 0, stream>>>(dst, cnt, batch, gcnt);
    scan_block2<<<NB + NBG, 256, 0, stream>>>(cnt, offs, bsum, gcnt, goffs, gsum, NB);
    scan_base2<<<2, 256, 0, stream>>>(bsum, bbase, NB, offs + N_NODES,
                                      gsum, gbase, NBG, goffs + N_GRAPHS);
    scan_add2<<<NB + NBG, 256, 0, stream>>>(offs, bbase, cursor, goffs, gbase, NB);
    scatter_kernel<<<(N_EDGES + 255) / 256, 256, 0, stream>>>(src, dst, cursor, csr, N_EDGES);

    // ---- projection: h0 = relu([xh|xl|xh] @ [Whi;Whi;Wlo] + b) -> hA ----
    gemm_plane4<1><<<(N_NODES + 255) / 256, 512, 0, stream>>>(
        xs, XSTR, N_NODES, XSTR, Bp, nullptr, b_proj, hA, 1);

    // ---- fused GIN layers (gather + MLP in one kernel; ping-pong planes) ----
    const int GBM = (N_NODES + 127) / 128;   // 391
    unsigned short* cur = hA;
    unsigned short* nxt = hBx;
    for (int i = 0; i < DEPTH; ++i) {
        gin_layer<<<GBM, 512, 0, stream>>>(
            cur, offs, csr, N_NODES,
            w1H + (size_t)i * LAYER_SZ, w1L + (size_t)i * LAYER_SZ, b1 + (size_t)i * HID,
            w2H + (size_t)i * LAYER_SZ, w2L + (size_t)i * LAYER_SZ, b2 + (size_t)i * HID,
            nxt, (i < DEPTH - 1) ? 1 : 0);
        unsigned short* t = cur; cur = nxt; nxt = t;
    }

    // ---- segmented pool (batch sorted) ----
    pool_seg<<<N_GRAPHS, 64, 0, stream>>>(cur, goffs, pooled);

    // ---- readout: prelu(pooled @ W_sp + b_sp) ----
    gemm_f32A<<<dim3(4, (N_GRAPHS + 63) / 64), 256, 0, stream>>>(
        pooled, PSTR, N_GRAPHS, HID, 320, spH, spL, 320,
        b_sp, READOUT, (float*)d_out, READOUT, 2, prelu);
}

// Round 10
// 1019.545 us; speedup vs baseline: 1.2483x; 1.2483x over previous
//
#include <hip/hip_runtime.h>
#include <cstdint>

#define N_NODES 50000
#define N_EDGES 800000
#define N_GRAPHS 1024
#define NODE_IN 128
#define HID 300
#define DEPTH 5
#define READOUT 1024
#define PSTR 320   // plane row stride (elements): 640B rows
#define XSTR 384   // stacked proj plane stride
#define MROWS 224  // gin_mlp2 block rows (224 blocks = single round)

typedef float f32x4 __attribute__((ext_vector_type(4)));
typedef short bf16x8 __attribute__((ext_vector_type(8)));
typedef unsigned short us8 __attribute__((ext_vector_type(8)));

__device__ inline unsigned short f2bf(float v) {
    unsigned u = __float_as_uint(v);
    unsigned r = u + 0x7FFFu + ((u >> 16) & 1u);
    return (unsigned short)(r >> 16);
}
__device__ inline float bf2f(unsigned short h) {
    return __uint_as_float((unsigned)h << 16);
}
__device__ inline float bflo(unsigned u) { return __uint_as_float(u << 16); }
__device__ inline float bfhi(unsigned u) { return __uint_as_float(u & 0xFFFF0000u); }
__device__ inline unsigned packbf(float a, float b) {
    return (unsigned)f2bf(a) | ((unsigned)f2bf(b) << 16);
}

// ---------------------------------------------------------------- CSR build (merged)
__global__ void hist2(const int* __restrict__ dst, int* __restrict__ cnt,
                      const int* __restrict__ batch, int* __restrict__ gcnt) {
    int i = blockIdx.x * blockDim.x + threadIdx.x;
    if (i < N_EDGES) atomicAdd(&cnt[dst[i]], 1);
    else if (i < N_EDGES + N_NODES) atomicAdd(&gcnt[batch[i - N_EDGES]], 1);
}

__global__ __launch_bounds__(256)
void scan_block2(const int* __restrict__ cnt, int* __restrict__ offs, int* __restrict__ bsum,
                 const int* __restrict__ gcnt, int* __restrict__ goffs, int* __restrict__ gsum,
                 int nbn) {
    __shared__ int buf[256];
    int b = blockIdx.x;
    const int* in; int* out; int* bs; int n; int bi;
    if (b < nbn) { in = cnt; out = offs; bs = bsum; n = N_NODES; bi = b; }
    else { in = gcnt; out = goffs; bs = gsum; n = N_GRAPHS; bi = b - nbn; }
    int i = bi * 256 + (int)threadIdx.x;
    int v = (i < n) ? in[i] : 0;
    buf[threadIdx.x] = v;
    __syncthreads();
    for (int off = 1; off < 256; off <<= 1) {
        int t = ((int)threadIdx.x >= off) ? buf[threadIdx.x - off] : 0;
        __syncthreads();
        buf[threadIdx.x] += t;
        __syncthreads();
    }
    if (i < n) out[i] = buf[threadIdx.x] - v;
    if (threadIdx.x == 255) bs[bi] = buf[255];
}

__global__ __launch_bounds__(256)
void scan_base2(const int* __restrict__ bsum, int* __restrict__ bbase, int nbn, int* __restrict__ tot_n,
                const int* __restrict__ gsum, int* __restrict__ gbase, int nbg, int* __restrict__ tot_g) {
    __shared__ int buf[256];
    const int* bs; int* bb; int nb; int* tot;
    if (blockIdx.x == 0) { bs = bsum; bb = bbase; nb = nbn; tot = tot_n; }
    else { bs = gsum; bb = gbase; nb = nbg; tot = tot_g; }
    int v = ((int)threadIdx.x < nb) ? bs[threadIdx.x] : 0;
    buf[threadIdx.x] = v;
    __syncthreads();
    for (int off = 1; off < 256; off <<= 1) {
        int t = ((int)threadIdx.x >= off) ? buf[threadIdx.x - off] : 0;
        __syncthreads();
        buf[threadIdx.x] += t;
        __syncthreads();
    }
    if ((int)threadIdx.x < nb) bb[threadIdx.x] = buf[threadIdx.x] - v;
    if (threadIdx.x == 255) *tot = buf[255];
}

__global__ void scan_add2(int* __restrict__ offs, const int* __restrict__ bbase,
                          int* __restrict__ cursor,
                          int* __restrict__ goffs, const int* __restrict__ gbase, int nbn) {
    int b = blockIdx.x;
    if (b < nbn) {
        int i = b * 256 + (int)threadIdx.x;
        if (i < N_NODES) {
            int o = offs[i] + bbase[b];
            offs[i] = o;
            cursor[i] = o;
        }
    } else {
        int bi = b - nbn;
        int i = bi * 256 + (int)threadIdx.x;
        if (i < N_GRAPHS) goffs[i] += gbase[bi];
    }
}

__global__ void scatter_kernel(const int* __restrict__ src, const int* __restrict__ dst,
                               int* __restrict__ cursor, int* __restrict__ csr, int n) {
    int i = blockIdx.x * blockDim.x + threadIdx.x;
    if (i < n) {
        int p = atomicAdd(&cursor[dst[i]], 1);
        csr[p] = src[i];
    }
}

// ---------------------------------------------------------------- aggregation (bf16 planes)
__global__ __launch_bounds__(256)
void aggregate_bf16(const unsigned short* __restrict__ h, const int* __restrict__ offs,
                    const int* __restrict__ csr, unsigned short* __restrict__ out) {
    int wave = (int)((blockIdx.x * blockDim.x + threadIdx.x) >> 6);
    int lane = threadIdx.x & 63;
    if (wave >= N_NODES) return;
    float a0, a1, a2, a3, a4, a5;
    {
        const unsigned* r = (const unsigned*)(h + (size_t)wave * PSTR);
        uint2 u = *(const uint2*)&r[2 * lane];
        unsigned t = (lane < 32) ? r[128 + lane] : 0u;
        a0 = bflo(u.x); a1 = bfhi(u.x);
        a2 = bflo(u.y); a3 = bfhi(u.y);
        a4 = bflo(t);   a5 = bfhi(t);
    }
    int s = offs[wave], e = offs[wave + 1];
    int k = s;
    for (; k + 3 < e; k += 4) {
        const unsigned* r0 = (const unsigned*)(h + (size_t)csr[k] * PSTR);
        const unsigned* r1 = (const unsigned*)(h + (size_t)csr[k + 1] * PSTR);
        const unsigned* r2 = (const unsigned*)(h + (size_t)csr[k + 2] * PSTR);
        const unsigned* r3 = (const unsigned*)(h + (size_t)csr[k + 3] * PSTR);
        uint2 x0 = *(const uint2*)&r0[2 * lane];
        uint2 x1 = *(const uint2*)&r1[2 * lane];
        uint2 x2 = *(const uint2*)&r2[2 * lane];
        uint2 x3 = *(const uint2*)&r3[2 * lane];
        unsigned t0 = 0, t1 = 0, t2 = 0, t3 = 0;
        if (lane < 32) {
            t0 = r0[128 + lane]; t1 = r1[128 + lane];
            t2 = r2[128 + lane]; t3 = r3[128 + lane];
        }
        a0 += bflo(x0.x) + bflo(x1.x) + bflo(x2.x) + bflo(x3.x);
        a1 += bfhi(x0.x) + bfhi(x1.x) + bfhi(x2.x) + bfhi(x3.x);
        a2 += bflo(x0.y) + bflo(x1.y) + bflo(x2.y) + bflo(x3.y);
        a3 += bfhi(x0.y) + bfhi(x1.y) + bfhi(x2.y) + bfhi(x3.y);
        a4 += bflo(t0) + bflo(t1) + bflo(t2) + bflo(t3);
        a5 += bfhi(t0) + bfhi(t1) + bfhi(t2) + bfhi(t3);
    }
    for (; k < e; ++k) {
        const unsigned* r = (const unsigned*)(h + (size_t)csr[k] * PSTR);
        uint2 u = *(const uint2*)&r[2 * lane];
        unsigned t = (lane < 32) ? r[128 + lane] : 0u;
        a0 += bflo(u.x); a1 += bfhi(u.x);
        a2 += bflo(u.y); a3 += bfhi(u.y);
        a4 += bflo(t);   a5 += bfhi(t);
    }
    unsigned* o = (unsigned*)(out + (size_t)wave * PSTR);
    uint2 w; w.x = packbf(a0, a1); w.y = packbf(a2, a3);
    *(uint2*)&o[2 * lane] = w;
    if (lane < 32) o[128 + lane] = (lane < 22) ? packbf(a4, a5) : 0u;
}

// ---------------------------------------------------------------- weight pre-split
// z<10: hidden W -> stacked [320 rows][640]: [Whi | Wlo] per row (transposed)
// z==10: W_sp -> hi/lo [1280][320]; z==11: Wproj -> Bp [320][384] = [Whi|Whi|Wlo]
__global__ __launch_bounds__(256)
void split_all(const float* __restrict__ W1, const float* __restrict__ W2,
               const float* __restrict__ Wsp, const float* __restrict__ Wproj,
               unsigned short* __restrict__ w1S, unsigned short* __restrict__ w2S,
               unsigned short* __restrict__ spH, unsigned short* __restrict__ spL,
               unsigned short* __restrict__ Bp) {
    __shared__ float tile[32][33];
    const int STK_SZ = 320 * 640;
    int z = blockIdx.z;
    const float* W;
    int K, N;
    if (z < 10) {
        if (blockIdx.x >= 10) return;
        int l = z % 5;
        W = (z < 5 ? W1 : W2) + (size_t)l * HID * HID;
        K = HID; N = HID;
    } else if (z == 10) {
        W = Wsp; K = HID; N = READOUT;
    } else {
        if (blockIdx.x >= 10 || blockIdx.y >= 4) return;
        W = Wproj; K = NODE_IN; N = HID;
    }
    int n0 = blockIdx.x * 32, k0 = blockIdx.y * 32;
    int tx = threadIdx.x & 31, ty = threadIdx.x >> 5;
#pragma unroll
    for (int r = 0; r < 4; ++r) {
        int k = k0 + ty + r * 8, n = n0 + tx;
        tile[ty + r * 8][tx] = (k < K && n < N) ? W[(size_t)k * N + n] : 0.f;
    }
    __syncthreads();
#pragma unroll
    for (int r = 0; r < 4; ++r) {
        int n = n0 + ty + r * 8, k = k0 + tx;
        float v = tile[tx][ty + r * 8];
        unsigned short hb = f2bf(v);
        unsigned short lb = f2bf(v - bf2f(hb));
        if (z < 10) {
            unsigned short* S = (z < 5 ? w1S : w2S) + (size_t)(z % 5) * STK_SZ;
            S[(size_t)n * 640 + k] = hb;
            S[(size_t)n * 640 + 320 + k] = lb;
        } else if (z == 10) {
            spH[(size_t)n * 320 + k] = hb;
            spL[(size_t)n * 320 + k] = lb;
        } else {
            Bp[(size_t)n * XSTR + k] = hb;
            Bp[(size_t)n * XSTR + 128 + k] = hb;
            Bp[(size_t)n * XSTR + 256 + k] = lb;
        }
    }
}

// x -> xs plane [50000][384] = [xh | xl | xh]
__global__ void split_x(const float* __restrict__ x, unsigned short* __restrict__ xs) {
    int i = blockIdx.x * blockDim.x + threadIdx.x;
    if (i >= N_NODES * 64) return;
    int row = i >> 6, c = i & 63;
    float2 v = *(const float2*)&x[(size_t)row * NODE_IN + 2 * c];
    unsigned short h0 = f2bf(v.x), h1 = f2bf(v.y);
    unsigned short l0 = f2bf(v.x - bf2f(h0)), l1 = f2bf(v.y - bf2f(h1));
    unsigned hp = (unsigned)h0 | ((unsigned)h1 << 16);
    unsigned lp = (unsigned)l0 | ((unsigned)l1 << 16);
    unsigned* o = (unsigned*)(xs + (size_t)row * XSTR);
    o[c] = hp;
    o[64 + c] = lp;
    o[128 + c] = hp;
}

#define BSWZ(r, c) ((c) ^ (((r) >> 1) & 3))

// ---------------------------------------------------------------- fused MLP (stacked-K, 1 round)
// out = act2( relu( A @ [W1hi;W1lo] + b1 ) @ [W2hi;W2lo] + b2 ) -> bf16 plane
// 224 blocks x 224 rows, 512 thr (8 waves, 2M x 4N, wave tile 112x80).
// LDS: At 224x320 (140KB, XOR-swizzled) + Bs 320x32 (20KB) = 160KB exactly.
__global__ __launch_bounds__(512, 1)
void gin_mlp2(const unsigned short* __restrict__ Ap, int M,
              const unsigned short* __restrict__ B1, const float* __restrict__ b1,
              const unsigned short* __restrict__ B2, const float* __restrict__ b2,
              unsigned short* __restrict__ Op, int act2) {
    __shared__ __align__(16) unsigned short At[MROWS * 320];   // 143,360 B
    __shared__ __align__(16) unsigned short Bs[320 * 32];      //  20,480 B

    const int tid = threadIdx.x;
    const int bm = blockIdx.x * MROWS;
    const int wid = tid >> 6, lane = tid & 63;
    const int wm = wid >> 2, wn = wid & 3;
    const int lr = lane & 15, lk = lane >> 4;

    float b1v[5], b2v[5];
#pragma unroll
    for (int n = 0; n < 5; ++n) {
        int col = wn * 80 + n * 16 + lr;
        b1v[n] = (col < HID) ? b1[col] : 0.f;
        b2v[n] = (col < HID) ? b2[col] : 0.f;
    }

    us8 vB[3];
    auto LOADB = [&](const unsigned short* B, int t) {
        int k0 = t * 32;
#pragma unroll
        for (int i = 0; i < 3; ++i) {
            int q = i * 512 + tid;
            if (q < 1280) {
                int r = q >> 2, c = q & 3;
                vB[i] = *(const us8*)&B[(size_t)r * 640 + k0 + c * 8];
            }
        }
    };

    LOADB(B1, 0);   // in flight during A staging

    // ---- stage A (224 x 320, once) ----
#pragma unroll
    for (int i = 0; i < 18; ++i) {
        int g = i * 512 + tid;
        if (g < MROWS * 40) {
            int row = g / 40, c = g - row * 40;
            int grow = bm + row; if (grow >= M) grow = M - 1;
            us8 v = *(const us8*)&Ap[(size_t)grow * PSTR + c * 8];
            *(us8*)&At[row * 320 + (c ^ (row & 7)) * 8] = v;
        }
    }

    f32x4 acc[7][5];

    auto RUN = [&](const unsigned short* B) {
        for (int t = 0; t < 20; ++t) {
            __syncthreads();                 // prev reads done; Bs free; At visible
#pragma unroll
            for (int i = 0; i < 3; ++i) {
                int q = i * 512 + tid;
                if (q < 1280) {
                    int r = q >> 2, c = q & 3;
                    *(us8*)&Bs[r * 32 + BSWZ(r, c) * 8] = vB[i];
                }
            }
            if (t < 19) LOADB(B, t + 1);     // in flight under compute
            __syncthreads();                 // Bs ready
            bf16x8 aS[7];
            int ac = (t % 10) * 4 + lk;      // A col chunk (k' mod 320)
#pragma unroll
            for (int m = 0; m < 7; ++m) {
                int row = wm * 112 + m * 16 + lr;
                aS[m] = *(const bf16x8*)&At[row * 320 + (ac ^ (row & 7)) * 8];
            }
#pragma unroll
            for (int n = 0; n < 5; ++n) {
                int rb = wn * 80 + n * 16 + lr;
                bf16x8 bb = *(const bf16x8*)&Bs[rb * 32 + BSWZ(rb, lk) * 8];
#pragma unroll
                for (int m = 0; m < 7; ++m)
                    acc[m][n] = __builtin_amdgcn_mfma_f32_16x16x32_bf16(aS[m], bb, acc[m][n], 0, 0, 0);
            }
        }
    };

    // ---- GEMM1 ----
#pragma unroll
    for (int m = 0; m < 7; ++m)
#pragma unroll
        for (int n = 0; n < 5; ++n) acc[m][n] = (f32x4)0.f;
    RUN(B1);

    LOADB(B2, 0);          // prefetch GEMM2's first tile

    // ---- T = relu(acc + b1) -> At ----
    __syncthreads();       // all waves done reading At
#pragma unroll
    for (int n = 0; n < 5; ++n) {
        int col = wn * 80 + n * 16 + lr;
        int cc = col >> 3, cp = col & 7;
        float bv = b1v[n];
        bool vc = col < HID;
#pragma unroll
        for (int m = 0; m < 7; ++m) {
#pragma unroll
            for (int p = 0; p < 4; ++p) {
                int row = wm * 112 + m * 16 + lk * 4 + p;
                float v = vc ? fmaxf(acc[m][n][p] + bv, 0.f) : 0.f;
                At[row * 320 + ((cc ^ (row & 7)) * 8) + cp] = f2bf(v);
            }
        }
    }

    // ---- GEMM2 (RUN's first barrier covers T visibility) ----
#pragma unroll
    for (int m = 0; m < 7; ++m)
#pragma unroll
        for (int n = 0; n < 5; ++n) acc[m][n] = (f32x4)0.f;
    RUN(B2);

    // ---- epilogue: act2(acc + b2) -> At -> coalesced stores ----
    __syncthreads();
#pragma unroll
    for (int n = 0; n < 5; ++n) {
        int col = wn * 80 + n * 16 + lr;
        int cc = col >> 3, cp = col & 7;
        float bv = b2v[n];
        bool vc = col < HID;
#pragma unroll
        for (int m = 0; m < 7; ++m) {
#pragma unroll
            for (int p = 0; p < 4; ++p) {
                int row = wm * 112 + m * 16 + lk * 4 + p;
                float v = vc ? (acc[m][n][p] + bv) : 0.f;
                if (act2) v = fmaxf(v, 0.f);
                At[row * 320 + ((cc ^ (row & 7)) * 8) + cp] = f2bf(v);
            }
        }
    }
    __syncthreads();
#pragma unroll
    for (int i = 0; i < 18; ++i) {
        int g = i * 512 + tid;
        if (g < MROWS * 40) {
            int row = g / 40, c = g - row * 40;
            int grow = bm + row;
            if (grow < M)
                *(us8*)&Op[(size_t)grow * PSTR + c * 8] =
                    *(const us8*)&At[row * 320 + (c ^ (row & 7)) * 8];
        }
    }
}

// ---------------------------------------------------------------- projection GEMM (dbuf, plane out)
template<int NPL>
__global__ __launch_bounds__(512)
void gemm_plane4(const unsigned short* __restrict__ Ap, int astr, int M, int KP,
                 const unsigned short* __restrict__ BH, const unsigned short* __restrict__ BL,
                 const float* __restrict__ bias, unsigned short* __restrict__ Op, int act) {
    constexpr int BITER = (NPL * 1280 + 511) / 512;
    __shared__ __align__(16) unsigned short As[2][256 * 40];
    __shared__ __align__(16) unsigned short Bs[2][NPL * 10240];

    const int tid = threadIdx.x;
    const int bm = blockIdx.x * 256;
    const int wid = tid >> 6, lane = tid & 63;
    const int wm = wid >> 2, wn = wid & 3;
    const int lr = lane & 15, lk = lane >> 4;
    const int arow = tid >> 1, ach = (tid & 1) * 2;
    int agr = bm + arow; if (agr >= M) agr = M - 1;
    const unsigned short* aSrc = Ap + (size_t)agr * astr + ach * 8;

    const unsigned short* bsrc[BITER];
    int bldso[BITER];
    bool bval[BITER];
#pragma unroll
    for (int i = 0; i < BITER; ++i) {
        int qq = i * 512 + tid;
        bval[i] = qq < NPL * 1280;
        int p = (NPL == 2 && qq >= 1280) ? 1 : 0;
        int q2 = qq - p * 1280;
        int r = q2 >> 2, c = q2 & 3;
        const unsigned short* base = p ? BL : BH;
        bsrc[i] = base + (size_t)r * KP + c * 8;
        bldso[i] = p * 10240 + r * 32 + BSWZ(r, c) * 8;
    }

    f32x4 acc[8][5];
#pragma unroll
    for (int m = 0; m < 8; ++m)
#pragma unroll
        for (int n = 0; n < 5; ++n) acc[m][n] = (f32x4)0.f;

    us8 vA0, vA1, vB[BITER];
    auto LOADS = [&](int t) {
        int k0 = t * 32;
        vA0 = *(const us8*)&aSrc[k0];
        vA1 = *(const us8*)&aSrc[k0 + 8];
#pragma unroll
        for (int i = 0; i < BITER; ++i)
            if (bval[i]) vB[i] = *(const us8*)&bsrc[i][k0];
    };
    auto WRITE = [&](int b) {
        *(us8*)&As[b][arow * 40 + ach * 8] = vA0;
        *(us8*)&As[b][arow * 40 + ach * 8 + 8] = vA1;
#pragma unroll
        for (int i = 0; i < BITER; ++i)
            if (bval[i]) *(us8*)&Bs[b][bldso[i]] = vB[i];
    };

    const int nt = KP / 32;
    LOADS(0);
    WRITE(0);
    int buf = 0;
    for (int t = 0; t < nt; ++t) {
        bool more = (t + 1 < nt);
        if (more) LOADS(t + 1);
        __syncthreads();
        bf16x8 aS[8];
#pragma unroll
        for (int m = 0; m < 8; ++m)
            aS[m] = *(const bf16x8*)&As[buf][(wm * 128 + m * 16 + lr) * 40 + lk * 8];
#pragma unroll
        for (int n = 0; n < 5; ++n) {
            int rb = wn * 80 + n * 16 + lr;
            int sc = rb * 32 + BSWZ(rb, lk) * 8;
            bf16x8 bh = *(const bf16x8*)&Bs[buf][sc];
#pragma unroll
            for (int m = 0; m < 8; ++m)
                acc[m][n] = __builtin_amdgcn_mfma_f32_16x16x32_bf16(aS[m], bh, acc[m][n], 0, 0, 0);
            if (NPL == 2) {
                bf16x8 bl = *(const bf16x8*)&Bs[buf][10240 + sc];
#pragma unroll
                for (int m = 0; m < 8; ++m)
                    acc[m][n] = __builtin_amdgcn_mfma_f32_16x16x32_bf16(aS[m], bl, acc[m][n], 0, 0, 0);
            }
        }
        if (more) WRITE(buf ^ 1);
        buf ^= 1;
    }
#pragma unroll
    for (int n = 0; n < 5; ++n) {
        int col = wn * 80 + n * 16 + lr;
        bool vc = col < HID;
        float bv = vc ? bias[col] : 0.f;
#pragma unroll
        for (int m = 0; m < 8; ++m) {
            int rbase = bm + wm * 128 + m * 16 + lk * 4;
#pragma unroll
            for (int p = 0; p < 4; ++p) {
                int row = rbase + p;
                if (row >= M) continue;
                float v = vc ? (acc[m][n][p] + bv) : 0.f;
                if (act == 1) v = fmaxf(v, 0.f);
                Op[(size_t)row * PSTR + col] = f2bf(v);
            }
        }
    }
}

// ---------------------------------------------------------------- GEMM: fp32 A (readout only)
__global__ __launch_bounds__(256)
void gemm_f32A(const float* __restrict__ A, int lda, int M, int K, int KP,
               const unsigned short* __restrict__ BH, const unsigned short* __restrict__ BL, int KPB,
               const float* __restrict__ bias, int N,
               float* __restrict__ C, int ldc, int act, const float* __restrict__ prelu) {
    __shared__ __align__(16) unsigned short AsH[64 * 40];
    __shared__ __align__(16) unsigned short AsL[64 * 40];
    __shared__ __align__(16) unsigned short BsH[320 * 40];
    __shared__ __align__(16) unsigned short BsL[320 * 40];

    const int tid = threadIdx.x;
    const int bm = blockIdx.y * 64;
    const int bn = blockIdx.x * 320;
    const int wid = tid >> 6, lane = tid & 63;
    const int lr = lane & 15, lk = lane >> 4;
    const int ar = tid >> 2, ac = tid & 3;

    f32x4 acc[4][5];
#pragma unroll
    for (int m = 0; m < 4; ++m)
#pragma unroll
        for (int n = 0; n < 5; ++n) acc[m][n] = (f32x4)0.f;

    for (int k0 = 0; k0 < KP; k0 += 32) {
        {
            int gm = bm + ar;
            int k = k0 + ac * 8;
            float v[8];
#pragma unroll
            for (int j = 0; j < 8; ++j) v[j] = 0.f;
            if (gm < M) {
                if (k + 7 < K) {
                    float4 p0 = *(const float4*)&A[(size_t)gm * lda + k];
                    float4 p1 = *(const float4*)&A[(size_t)gm * lda + k + 4];
                    v[0] = p0.x; v[1] = p0.y; v[2] = p0.z; v[3] = p0.w;
                    v[4] = p1.x; v[5] = p1.y; v[6] = p1.z; v[7] = p1.w;
                } else {
#pragma unroll
                    for (int j = 0; j < 8; ++j)
                        if (k + j < K) v[j] = A[(size_t)gm * lda + k + j];
                }
            }
            us8 h, l;
#pragma unroll
            for (int j = 0; j < 8; ++j) {
                unsigned short hb = f2bf(v[j]);
                h[j] = hb;
                l[j] = f2bf(v[j] - bf2f(hb));
            }
            *(us8*)&AsH[ar * 40 + ac * 8] = h;
            *(us8*)&AsL[ar * 40 + ac * 8] = l;
        }
#pragma unroll
        for (int p = 0; p < 5; ++p) {
            int r = ar + p * 64;
            size_t gb = (size_t)(bn + r) * KPB + k0 + ac * 8;
            *(us8*)&BsH[r * 40 + ac * 8] = *(const us8*)&BH[gb];
            *(us8*)&BsL[r * 40 + ac * 8] = *(const us8*)&BL[gb];
        }
        __syncthreads();
        bf16x8 aH[4], aL[4];
#pragma unroll
        for (int m = 0; m < 4; ++m) {
            aH[m] = *(const bf16x8*)&AsH[(m * 16 + lr) * 40 + lk * 8];
            aL[m] = *(const bf16x8*)&AsL[(m * 16 + lr) * 40 + lk * 8];
        }
#pragma unroll
        for (int n = 0; n < 5; ++n) {
            int r = wid * 80 + n * 16 + lr;
            bf16x8 bh = *(const bf16x8*)&BsH[r * 40 + lk * 8];
            bf16x8 bl = *(const bf16x8*)&BsL[r * 40 + lk * 8];
#pragma unroll
            for (int m = 0; m < 4; ++m) {
                acc[m][n] = __builtin_amdgcn_mfma_f32_16x16x32_bf16(aH[m], bh, acc[m][n], 0, 0, 0);
                acc[m][n] = __builtin_amdgcn_mfma_f32_16x16x32_bf16(aH[m], bl, acc[m][n], 0, 0, 0);
                acc[m][n] = __builtin_amdgcn_mfma_f32_16x16x32_bf16(aL[m], bh, acc[m][n], 0, 0, 0);
            }
        }
        __syncthreads();
    }
    float slope = (act == 2) ? prelu[0] : 0.f;
#pragma unroll
    for (int n = 0; n < 5; ++n) {
        int col = bn + wid * 80 + n * 16 + lr;
        bool vc = col < N;
        float bv = vc ? bias[col] : 0.f;
#pragma unroll
        for (int m = 0; m < 4; ++m) {
            int rbase = bm + m * 16 + lk * 4;
#pragma unroll
            for (int p = 0; p < 4; ++p) {
                int row = rbase + p;
                if (row >= M) continue;
                float v = vc ? (acc[m][n][p] + bv) : 0.f;
                if (act == 1) v = fmaxf(v, 0.f);
                else if (act == 2) v = (v >= 0.f) ? v : slope * v;
                if (vc) C[(size_t)row * ldc + col] = v;
            }
        }
    }
}

// ---------------------------------------------------------------- segmented pool
__global__ __launch_bounds__(64)
void pool_seg(const unsigned short* __restrict__ h, const int* __restrict__ goffs,
              float* __restrict__ pooled) {
    int g = blockIdx.x;
    int lane = threadIdx.x;
    int s = goffs[g], e = goffs[g + 1];
    float a0 = 0.f, a1 = 0.f, a2 = 0.f, a3 = 0.f, a4 = 0.f, a5 = 0.f;
    for (int node = s; node < e; ++node) {
        const unsigned* r = (const unsigned*)(h + (size_t)node * PSTR);
        uint2 u = *(const uint2*)&r[2 * lane];
        unsigned t = (lane < 32) ? r[128 + lane] : 0u;
        a0 += bflo(u.x); a1 += bfhi(u.x);
        a2 += bflo(u.y); a3 += bfhi(u.y);
        a4 += bflo(t);   a5 += bfhi(t);
    }
    float* pr = pooled + (size_t)g * PSTR;
    *(float4*)&pr[4 * lane] = make_float4(a0, a1, a2, a3);
    if (lane < 32) *(float2*)&pr[256 + 2 * lane] = make_float2(a4, a5);
}

// ---------------------------------------------------------------- launch
extern "C" void kernel_launch(void* const* d_in, const int* in_sizes, int n_in,
                              void* d_out, int out_size, void* d_ws, size_t ws_size,
                              hipStream_t stream) {
    const float* x      = (const float*)d_in[0];
    const int*   eidx   = (const int*)d_in[1];
    const int*   batch  = (const int*)d_in[2];
    const float* W_proj = (const float*)d_in[3];
    const float* b_proj = (const float*)d_in[4];
    const float* W1     = (const float*)d_in[5];
    const float* b1     = (const float*)d_in[6];
    const float* W2     = (const float*)d_in[7];
    const float* b2     = (const float*)d_in[8];
    const float* W_sp   = (const float*)d_in[9];
    const float* b_sp   = (const float*)d_in[10];
    const float* prelu  = (const float*)d_in[11];

    const int* src = eidx;
    const int* dst = eidx + N_EDGES;

    const size_t PLANE  = (size_t)N_NODES * PSTR + 64;
    const size_t XPLANE = (size_t)N_NODES * XSTR + 64;
    const int STK_SZ = 320 * 640;
    const int SP_SZ  = 1280 * 320;
    const int BP_SZ  = 320 * XSTR;
    const int NB  = (N_NODES + 255) / 256;   // 196
    const int NBG = (N_GRAPHS + 255) / 256;  // 4

    unsigned short* hA  = (unsigned short*)d_ws;       // PLANE
    unsigned short* hBx = hA + PLANE;                  // XPLANE (xs overlay)
    unsigned short* xs  = hBx;
    float* pooled = (float*)(hBx + XPLANE);
    unsigned short* w1S = (unsigned short*)(pooled + (size_t)N_GRAPHS * PSTR + 16);
    unsigned short* w2S = w1S + 5 * (size_t)STK_SZ;
    unsigned short* spH = w2S + 5 * (size_t)STK_SZ;
    unsigned short* spL = spH + SP_SZ;
    unsigned short* Bp  = spL + SP_SZ;
    int* cnt    = (int*)(((uintptr_t)(Bp + BP_SZ) + 15) & ~(uintptr_t)15);
    int* gcnt   = cnt + N_NODES;
    int* bsum   = gcnt + N_GRAPHS;
    int* bbase  = bsum + 256;
    int* gsum   = bbase + 256;
    int* gbase  = gsum + 256;
    int* offs   = gbase + 256;
    int* goffs  = offs + N_NODES + 1;
    int* cursor = goffs + N_GRAPHS + 1;
    int* csr    = cursor + N_NODES;
    size_t needed = (size_t)((uintptr_t)(csr + N_EDGES) - (uintptr_t)d_ws);
    if (ws_size < needed) return;

    // ---- weight pre-split (one launch) ----
    split_all<<<dim3(40, 10, 12), 256, 0, stream>>>(W1, W2, W_sp, W_proj,
                                                    w1S, w2S, spH, spL, Bp);
    // ---- input split ----
    split_x<<<(N_NODES * 64 + 255) / 256, 256, 0, stream>>>(x, xs);

    // ---- CSR + graph offsets (merged chains) ----
    hipMemsetAsync(cnt, 0, (N_NODES + N_GRAPHS) * sizeof(int), stream);
    hist2<<<(N_EDGES + N_NODES + 255) / 256, 256, 0, stream>>>(dst, cnt, batch, gcnt);
    scan_block2<<<NB + NBG, 256, 0, stream>>>(cnt, offs, bsum, gcnt, goffs, gsum, NB);
    scan_base2<<<2, 256, 0, stream>>>(bsum, bbase, NB, offs + N_NODES,
                                      gsum, gbase, NBG, goffs + N_GRAPHS);
    scan_add2<<<NB + NBG, 256, 0, stream>>>(offs, bbase, cursor, goffs, gbase, NB);
    scatter_kernel<<<(N_EDGES + 255) / 256, 256, 0, stream>>>(src, dst, cursor, csr, N_EDGES);

    // ---- projection: h0 = relu([xh|xl|xh] @ [Whi;Whi;Wlo] + b) -> hA ----
    gemm_plane4<1><<<(N_NODES + 255) / 256, 512, 0, stream>>>(
        xs, XSTR, N_NODES, XSTR, Bp, nullptr, b_proj, hA, 1);

    // ---- GIN layers: agg (separate, high-occupancy) + 1-round fused MLP ----
    const int GBM = (N_NODES + MROWS - 1) / MROWS;   // 224 blocks
    unsigned short* cur = hA;
    unsigned short* agp = hBx;
    for (int i = 0; i < DEPTH; ++i) {
        aggregate_bf16<<<(N_NODES * 64 + 255) / 256, 256, 0, stream>>>(cur, offs, csr, agp);
        gin_mlp2<<<GBM, 512, 0, stream>>>(
            agp, N_NODES,
            w1S + (size_t)i * STK_SZ, b1 + (size_t)i * HID,
            w2S + (size_t)i * STK_SZ, b2 + (size_t)i * HID,
            cur, (i < DEPTH - 1) ? 1 : 0);
    }

    // ---- segmented pool (batch sorted) ----
    pool_seg<<<N_GRAPHS, 64, 0, stream>>>(cur, goffs, pooled);

    // ---- readout: prelu(pooled @ W_sp + b_sp) ----
    gemm_f32A<<<dim3(4, (N_GRAPHS + 63) / 64), 256, 0, stream>>>(
        pooled, PSTR, N_GRAPHS, HID, 320, spH, spL, 320,
        b_sp, READOUT, (float*)d_out, READOUT, 2, prelu);
}